// Round 12
// baseline (139.350 us; speedup 1.0000x reference)
//
#include <hip/hip_runtime.h>
#include <stdint.h>

typedef __attribute__((ext_vector_type(4))) int i32x4;
typedef __attribute__((ext_vector_type(4))) float f32x4;

__device__ inline float wave_max(float v){ for(int o=32;o;o>>=1) v=fmaxf(v,__shfl_xor(v,o)); return v; }
__device__ inline float wave_min(float v){ for(int o=32;o;o>>=1) v=fminf(v,__shfl_xor(v,o)); return v; }
__device__ inline int   wave_sum(int v){ for(int o=32;o;o>>=1) v+=__shfl_xor(v,o); return v; }

// stage 1: per-block max -> partials[blockIdx.x]  (no atomics)
__global__ void k_xmax_partial(const float* __restrict__ x, long long n4,
                               float* __restrict__ partials){
  long long i = (long long)blockIdx.x*blockDim.x + threadIdx.x;
  long long stride = (long long)gridDim.x*blockDim.x;
  const float4* x4 = (const float4*)x;
  float m = 0.f;
  for(; i < n4; i += stride){
    float4 v = x4[i];
    m = fmaxf(m, fmaxf(fmaxf(v.x,v.y),fmaxf(v.z,v.w)));
  }
  m = wave_max(m);
  __shared__ float sm[4];
  int lane = threadIdx.x & 63, wid = threadIdx.x >> 6;
  if(lane==0) sm[wid] = m;
  __syncthreads();
  if(threadIdx.x==0)
    partials[blockIdx.x] = fmaxf(fmaxf(sm[0],sm[1]),fmaxf(sm[2],sm[3]));
}

// MFMA-fragment-tiled layout for q buffers:
// tile = 16 rows x 64 K = 1024 B; within tile, byte = ((k&63)>>4)*256 + (row&15)*16 + (k&15)
// -> a wave's frag load is ONE contiguous 1KB global_load_dwordx4 (lane*16).
__device__ inline size_t qoff(int row, int k0, int din){
  return ((size_t)(row>>4)*(din>>6) + (k0>>6))*1024
       + (size_t)(((k0&63)>>4)*256 + (row&15)*16 + (k0&15));
}

// one block (256 thr) per output channel row (bias folded in gemm epilogue)
__global__ void k_wstat(const float* __restrict__ w,
                        const int* __restrict__ wbit,
                        float* __restrict__ scale_w, float* __restrict__ zp_w,
                        float* __restrict__ winv,
                        int* __restrict__ cint, char* __restrict__ qw, int din){
  int row = blockIdx.x, tid = threadIdx.x;
  int lane = tid & 63, wid = tid >> 6;
  const float4* wr4 = (const float4*)(w + (long long)row*din);
  float4 a = wr4[tid*2], b = wr4[tid*2+1];
  float v[8] = {a.x,a.y,a.z,a.w,b.x,b.y,b.z,b.w};
  float mn = v[0], mx = v[0];
  for(int j=1;j<8;j++){ mn=fminf(mn,v[j]); mx=fmaxf(mx,v[j]); }
  float wmn = wave_min(mn), wmx = wave_max(mx);
  __shared__ float smn[4], smx[4];
  __shared__ float s_sw, s_zp;
  if(lane==0){ smn[wid]=wmn; smx[wid]=wmx; }
  __syncthreads();
  if(tid==0){
    float fmn = fminf(fminf(smn[0],smn[1]),fminf(smn[2],smn[3]));
    float fmx = fmaxf(fmaxf(smx[0],smx[1]),fmaxf(smx[2],smx[3]));
    int n = 1 << *wbit;
    float nm1 = (float)(n-1);
    float rngc = fmaxf(__fsub_rn(fmx, fmn), 1e-8f);
    float sw = __fdiv_rn(nm1, rngc);
    float zp = __fmul_rn(sw, fmn);
    s_sw = sw; s_zp = zp;
    scale_w[row] = sw; zp_w[row] = zp;
    winv[row] = __fdiv_rn(rngc, nm1);
  }
  __syncthreads();
  float sw = s_sw, zp = s_zp;
  int qsum = 0; uint32_t lo = 0, hi = 0;
  for(int j=0;j<8;j++){
    int q = (int)rintf(__fsub_rn(__fmul_rn(sw, v[j]), zp));   // exact replication, no fma
    qsum += q;
    uint32_t u = (uint32_t)((q - 128) & 0xff);
    if(j<4) lo |= u << (8*j); else hi |= u << (8*(j-4));
  }
  uint32_t* p = (uint32_t*)(qw + qoff(row, tid*8, din));
  p[0] = lo; p[1] = hi;
  int wsum = wave_sum(qsum);
  __shared__ int ssum[4];
  if(lane==0) ssum[wid] = wsum;
  __syncthreads();
  if(tid==0){
    int Sb = ssum[0]+ssum[1]+ssum[2]+ssum[3];
    cint[row] = 128*Sb - 128*128*din;
  }
}

// one block (256 thr) per token row; reduces partials inline
__global__ void k_xquant(const float* __restrict__ x, const int* __restrict__ wbit,
                         const float* __restrict__ partials, int nPart,
                         char* __restrict__ qx, int* __restrict__ Sa, int din){
  int row = blockIdx.x, tid = threadIdx.x;
  int lane = tid & 63, wid = tid >> 6;
  float mm = 0.f;
  for(int i=tid;i<nPart;i+=256) mm = fmaxf(mm, partials[i]);
  mm = wave_max(mm);
  __shared__ float sm[4];
  if(lane==0) sm[wid] = mm;
  __syncthreads();
  const float xmax = fmaxf(fmaxf(sm[0],sm[1]),fmaxf(sm[2],sm[3]));
  int n = 1 << *wbit;
  float nm1 = (float)(n-1);
  float sx = __fdiv_rn(nm1, fmaxf(xmax, 1e-8f));
  const float4* xr4 = (const float4*)(x + (long long)row*din);
  float4 a = xr4[tid*2], b = xr4[tid*2+1];
  float v[8] = {a.x,a.y,a.z,a.w,b.x,b.y,b.z,b.w};
  int qsum = 0; uint32_t lo = 0, hi = 0;
  for(int j=0;j<8;j++){
    int q = (int)rintf(__fmul_rn(sx, v[j]));
    qsum += q;
    uint32_t u = (uint32_t)((q - 128) & 0xff);
    if(j<4) lo |= u << (8*j); else hi |= u << (8*(j-4));
  }
  uint32_t* p = (uint32_t*)(qx + qoff(row, tid*8, din));
  p[0] = lo; p[1] = hi;
  int wsum = wave_sum(qsum);
  __shared__ int ssum[4];
  if(lane==0) ssum[wid] = wsum;
  __syncthreads();
  if(tid==0) Sa[row] = ssum[0]+ssum[1]+ssum[2]+ssum[3];
}

// ======= 256x256 i8 GEMM: ALL-REGISTER main loop (no LDS, no barriers) =======
// qx/qw are fragment-tiled, so each frag = one coalesced 1KB load from L2.
// 8 waves (2Mx4N), per-wave 128x64; 12 loads + 32 MFMA per K-step (K=64),
// 2-deep register double-buffer; waves fully independent -> MFMA/VMEM overlap
// across the CU's 8 waves without lockstep. XCD-rect keeps qx/qw L2-local.
__global__ __launch_bounds__(512, 2) void k_gemm(
    const char* __restrict__ qx, const char* __restrict__ qw,
    const int* __restrict__ Sa, const int* __restrict__ cint,
    const float* __restrict__ scale_w, const float* __restrict__ winv,
    const float* __restrict__ zp_w, const float* __restrict__ bias,
    const int* __restrict__ wbit, const float* __restrict__ partials, int nPart,
    float* __restrict__ out, int T, int dout, int din){
  __shared__ float ebuf[32*256];   // epilogue bounce only (32 KiB)
  const int tid = threadIdx.x, lane = tid & 63, wid = tid >> 6;
  const int wr = wid >> 2, wc = wid & 3;
  const int nkb = din >> 6;        // K-steps of 64

  // ---- XCD-rect block -> tile mapping ----
  const int bid = blockIdx.x;
  const int nTN = dout >> 8, nTM = T >> 8;
  int tileM, tileN;
  if(nTM == 32 && nTN == 8){
    const int rect = bid & 7, loc = bid >> 3;
    tileM = (rect >> 1)*8 + (loc & 7);
    tileN = (rect & 1)*4 + (loc >> 3);
  } else {
    tileN = bid % nTN; tileM = bid / nTN;
  }

  const char* aB0 = qx + ((size_t)(tileM*16 + wr*8)*nkb)*1024 + (size_t)lane*16;
  const char* bB0 = qw + ((size_t)(tileN*16 + wc*4)*nkb)*1024 + (size_t)lane*16;

  i32x4 acc[8][4] = {};
  i32x4 aX[8], bX[4], aY[8], bY[4];

#define LD(AF, BF, KT) do{ \
    _Pragma("unroll") \
    for(int mi=0;mi<8;++mi) AF[mi] = *(const i32x4*)(aB0 + ((size_t)mi*nkb + (KT))*1024); \
    _Pragma("unroll") \
    for(int ni=0;ni<4;++ni) BF[ni] = *(const i32x4*)(bB0 + ((size_t)ni*nkb + (KT))*1024); }while(0)
#define FM(AF, BF) do{ \
    __builtin_amdgcn_s_setprio(1); \
    _Pragma("unroll") \
    for(int mi=0;mi<8;++mi){ _Pragma("unroll") \
      for(int ni=0;ni<4;++ni) \
        acc[mi][ni] = __builtin_amdgcn_mfma_i32_16x16x64_i8(AF[mi], BF[ni], acc[mi][ni], 0,0,0); } \
    __builtin_amdgcn_s_setprio(0); }while(0)

  LD(aX, bX, 0);
  for(int kt = 0; kt < nkb; kt += 2){
    if(kt + 1 < nkb) LD(aY, bY, kt+1);
    FM(aX, bX);
    if(kt + 2 < nkb) LD(aX, bX, kt+2);
    FM(aY, bY);
  }
#undef LD
#undef FM

  // ---- epilogue (lgkm-only barriers; nt-stores never drained) ----
#define EBAR do{ asm volatile("s_waitcnt lgkmcnt(0)" ::: "memory"); \
                 __builtin_amdgcn_s_barrier(); }while(0)

  float mm = 0.f;
  for(int i = tid; i < nPart; i += 512) mm = fmaxf(mm, partials[i]);
  mm = wave_max(mm);
  if(lane==0) ebuf[wid] = mm;
  EBAR;
  float xmax = 0.f;
  #pragma unroll
  for(int i=0;i<8;i++) xmax = fmaxf(xmax, ebuf[i]);
  EBAR;

  const int n = 1 << *wbit;
  const float nm1 = (float)(n-1);
  const float xmaxc = fmaxf(xmax, 1e-8f);
  const float sx = __fdiv_rn(nm1, xmaxc);
  const float inv_sx = __fdiv_rn(xmaxc, nm1);
  const int colL = tileN*256 + wc*64 + (lane & 15);
  const int rowL = tileM*256 + wr*128 + ((lane >> 4) * 4);
  float invc[4], zp4[4]; int ci4[4];
  #pragma unroll
  for(int ni=0; ni<4; ++ni){
    int o = colL + ni*16;
    float sw = scale_w[o];
    float qbf = rintf(__fmul_rn(__fmul_rn(bias[o], sw), sx));
    qbf = fminf(fmaxf(qbf, -(float)(n+1)), (float)n);
    ci4[ni] = cint[o] + (int)qbf;
    invc[ni] = __fmul_rn(winv[o], inv_sx);
    zp4[ni]  = zp_w[o];
  }

  const int lwr  = wr*16 + ((lane >> 4) * 4);
  const int lcol = wc*64 + (lane & 15);
  #pragma unroll
  for(int mi=0; mi<8; ++mi){
    int rb = rowL + mi*16;
    int sav[4];
    #pragma unroll
    for(int r=0; r<4; ++r) sav[r] = Sa[rb + r];
    EBAR;                                    // prev-iter flush reads complete
    #pragma unroll
    for(int ni=0; ni<4; ++ni){
      #pragma unroll
      for(int r=0; r<4; ++r){
        int iv = acc[mi][ni][r] + 128*sav[r] + ci4[ni];
        float f = (float)iv + zp4[ni]*(float)sav[r];
        int row = lwr + r, col = lcol + ni*16;
        ebuf[row*256 + (col ^ (((row>>2)&3)<<4))] = __fmul_rn(f, invc[ni]);
      }
    }
    EBAR;                                    // ebuf writes visible
    #pragma unroll
    for(int p=0; p<4; ++p){
      int idx = tid + p*512;                 // 0..2047
      int lr = idx >> 6, cc = (idx & 63)*4;
      f32x4 v = *(const f32x4*)&ebuf[lr*256 + (cc ^ (((lr>>2)&3)<<4))];
      int gr = tileM*256 + (lr>>4)*128 + mi*16 + (lr&15);
      __builtin_nontemporal_store(v, (f32x4*)&out[(long long)gr*dout + tileN*256 + cc]);
    }
  }
#undef EBAR
}

extern "C" void kernel_launch(void* const* d_in, const int* in_sizes, int n_in,
                              void* d_out, int out_size, void* d_ws, size_t ws_size,
                              hipStream_t stream){
  const float* x    = (const float*)d_in[0];
  const float* w    = (const float*)d_in[1];
  const float* bias = (const float*)d_in[2];
  const int*   wbit = (const int*)d_in[3];
  int dout = in_sizes[2];
  int din  = in_sizes[1] / dout;
  int T    = in_sizes[0] / din;

  const int NPART = 2048;
  char* ws = (char*)d_ws;
  size_t off = 256;
  float* partials = (float*)(ws + off); off += 4*(size_t)NPART;
  float* scale_w = (float*)(ws + off); off += 4*(size_t)dout;
  float* zp_w    = (float*)(ws + off); off += 4*(size_t)dout;
  float* winv    = (float*)(ws + off); off += 4*(size_t)dout;
  int*   cint    = (int*)(ws + off);   off += 4*(size_t)dout;
  int*   Sa      = (int*)(ws + off);   off += 4*(size_t)T;
  off = (off + 255) & ~(size_t)255;
  char*  qw      = ws + off;           off += (size_t)dout*din;
  char*  qx      = ws + off;           off += (size_t)T*din;

  long long n4 = (long long)T*din/4;
  k_xmax_partial<<<NPART, 256, 0, stream>>>(x, n4, partials);
  k_xquant<<<T, 256, 0, stream>>>(x, wbit, partials, NPART, qx, Sa, din);
  k_wstat<<<dout, 256, 0, stream>>>(w, wbit, scale_w, zp_w, winv, cint, qw, din);
  int nblk = (T/256) * (dout/256);
  k_gemm<<<nblk, 512, 0, stream>>>(qx, qw, Sa, cint, scale_w, winv, zp_w, bias,
                                   wbit, partials, NPART, (float*)d_out, T, dout, din);
}

// Round 13
// 88.600 us; speedup vs baseline: 1.5728x; 1.5728x over previous
//
#include <hip/hip_runtime.h>
#include <stdint.h>

typedef __attribute__((ext_vector_type(4)))  int   i32x4;
typedef __attribute__((ext_vector_type(16))) int   i32x16;
typedef __attribute__((ext_vector_type(4)))  float f32x4;

__device__ inline float wave_max(float v){ for(int o=32;o;o>>=1) v=fmaxf(v,__shfl_xor(v,o)); return v; }
__device__ inline float wave_min(float v){ for(int o=32;o;o>>=1) v=fminf(v,__shfl_xor(v,o)); return v; }
__device__ inline int   wave_sum(int v){ for(int o=32;o;o>>=1) v+=__shfl_xor(v,o); return v; }

__device__ inline void gload16(const void* g, void* l){
  __builtin_amdgcn_global_load_lds((const __attribute__((address_space(1))) char*)g,
                                   (__attribute__((address_space(3))) char*)l, 16, 0, 0);
}

// ===== merged: w-stat/quant for row blockIdx.x  +  x-max partial slice =====
__global__ void k_wstat_xmax(const float* __restrict__ w, const float* __restrict__ x,
                             long long n4, const int* __restrict__ wbit,
                             float* __restrict__ scale_w, float* __restrict__ zp_w,
                             float* __restrict__ winv, int* __restrict__ cint,
                             char* __restrict__ qw, float* __restrict__ partials, int din){
  int row = blockIdx.x, tid = threadIdx.x;
  int lane = tid & 63, wid = tid >> 6;
  // x-max slice (grid-stride)
  const float4* x4 = (const float4*)x;
  float m = 0.f;
  for(long long i = (long long)blockIdx.x*256 + tid; i < n4; i += (long long)gridDim.x*256){
    float4 v = x4[i];
    m = fmaxf(m, fmaxf(fmaxf(v.x,v.y),fmaxf(v.z,v.w)));
  }
  m = wave_max(m);
  __shared__ float sxm[4];
  if(lane==0) sxm[wid] = m;
  // w row stats
  const float4* wr4 = (const float4*)(w + (long long)row*din);
  float4 a = wr4[tid*2], b = wr4[tid*2+1];
  float v[8] = {a.x,a.y,a.z,a.w,b.x,b.y,b.z,b.w};
  float mn = v[0], mx = v[0];
  for(int j=1;j<8;j++){ mn=fminf(mn,v[j]); mx=fmaxf(mx,v[j]); }
  float wmn = wave_min(mn), wmx = wave_max(mx);
  __shared__ float smn[4], smx[4];
  __shared__ float s_sw, s_zp;
  if(lane==0){ smn[wid]=wmn; smx[wid]=wmx; }
  __syncthreads();
  if(tid==0){
    partials[row] = fmaxf(fmaxf(sxm[0],sxm[1]),fmaxf(sxm[2],sxm[3]));
    float fmn = fminf(fminf(smn[0],smn[1]),fminf(smn[2],smn[3]));
    float fmx = fmaxf(fmaxf(smx[0],smx[1]),fmaxf(smx[2],smx[3]));
    int n = 1 << *wbit;
    float nm1 = (float)(n-1);
    float rngc = fmaxf(__fsub_rn(fmx, fmn), 1e-8f);
    float sw = __fdiv_rn(nm1, rngc);
    float zp = __fmul_rn(sw, fmn);
    s_sw = sw; s_zp = zp;
    scale_w[row] = sw; zp_w[row] = zp;
    winv[row] = __fdiv_rn(rngc, nm1);
  }
  __syncthreads();
  float sw = s_sw, zp = s_zp;
  int qsum = 0; uint32_t lo = 0, hi = 0;
  for(int j=0;j<8;j++){
    int q = (int)rintf(__fsub_rn(__fmul_rn(sw, v[j]), zp));   // exact replication, no fma
    qsum += q;
    uint32_t u = (uint32_t)((q - 128) & 0xff);
    if(j<4) lo |= u << (8*j); else hi |= u << (8*(j-4));
  }
  uint32_t* qrow = (uint32_t*)(qw + (long long)row*din);
  qrow[tid*2] = lo; qrow[tid*2+1] = hi;
  int wsum = wave_sum(qsum);
  __shared__ int ssum[4];
  if(lane==0) ssum[wid] = wsum;
  __syncthreads();
  if(tid==0){
    int Sb = ssum[0]+ssum[1]+ssum[2]+ssum[3];
    cint[row] = 128*Sb - 128*128*din;
  }
}

// one block (256 thr) per token row; reduces partials inline
__global__ void k_xquant(const float* __restrict__ x, const int* __restrict__ wbit,
                         const float* __restrict__ partials, int nPart,
                         char* __restrict__ qx, int* __restrict__ Sa, int din){
  int row = blockIdx.x, tid = threadIdx.x;
  int lane = tid & 63, wid = tid >> 6;
  float mm = 0.f;
  for(int i=tid;i<nPart;i+=256) mm = fmaxf(mm, partials[i]);
  mm = wave_max(mm);
  __shared__ float sm[4];
  if(lane==0) sm[wid] = mm;
  __syncthreads();
  const float xmax = fmaxf(fmaxf(sm[0],sm[1]),fmaxf(sm[2],sm[3]));
  int n = 1 << *wbit;
  float nm1 = (float)(n-1);
  float sx = __fdiv_rn(nm1, fmaxf(xmax, 1e-8f));
  const float4* xr4 = (const float4*)(x + (long long)row*din);
  float4 a = xr4[tid*2], b = xr4[tid*2+1];
  float v[8] = {a.x,a.y,a.z,a.w,b.x,b.y,b.z,b.w};
  int qsum = 0; uint32_t lo = 0, hi = 0;
  for(int j=0;j<8;j++){
    int q = (int)rintf(__fmul_rn(sx, v[j]));
    qsum += q;
    uint32_t u = (uint32_t)((q - 128) & 0xff);
    if(j<4) lo |= u << (8*j); else hi |= u << (8*(j-4));
  }
  uint32_t* qrow = (uint32_t*)(qx + (long long)row*din);
  qrow[tid*2] = lo; qrow[tid*2+1] = hi;
  int wsum = wave_sum(qsum);
  __shared__ int ssum[4];
  if(lane==0) ssum[wid] = wsum;
  __syncthreads();
  if(tid==0) Sa[row] = ssum[0]+ssum[1]+ssum[2]+ssum[3];
}

// ===== 256x256 i8 GEMM: 4 waves, per-wave 128x128, mfma_i32_32x32x32_i8 =====
// LDS reads/K-tile/CU: 128KB (was 192KB at 8x 128x64) -> ops/LDS-byte +50%.
// 4 ksteps(K=32)/K-tile(128); only TWO {vmcnt(8)+barrier} per K-tile (constant
// counted: stage order A0,B0,A1,B1 of 4 loads each => exactly 8 in flight at
// every sync). Phases 1,3 unbarriered -> their ds_reads overlap prior MFMAs.
// LDS: [buf2][A 32K | B 32K], rows 64B, chunk-XOR swizzle (r3-proven).
#define AOFF(B,S) ((B)*65536 + (S)*16384)
#define BOFF(B,S) ((B)*65536 + 32768 + (S)*16384)

__global__ __launch_bounds__(256, 1) void k_gemm(
    const char* __restrict__ qx, const char* __restrict__ qw,
    const int* __restrict__ Sa, const int* __restrict__ cint,
    const float* __restrict__ scale_w, const float* __restrict__ winv,
    const float* __restrict__ zp_w, const float* __restrict__ bias,
    const int* __restrict__ wbit, const float* __restrict__ partials, int nPart,
    float* __restrict__ out, int T, int dout, int din){
  extern __shared__ char lds[];   // 131072
  const int tid = threadIdx.x, lane = tid & 63, wid = tid >> 6;
  const int wr = wid >> 1, wc = wid & 1;
  const int nt = din / 128;

  // XCD-rect block -> tile mapping
  const int bid = blockIdx.x;
  const int nTN = dout >> 8, nTM = T >> 8;
  int tileM, tileN;
  if(nTM == 32 && nTN == 8){
    const int rect = bid & 7, loc = bid >> 3;
    tileM = (rect >> 1)*8 + (loc & 7);
    tileN = (rect & 1)*4 + (loc >> 3);
  } else {
    tileN = bid % nTN; tileM = bid / nTN;
  }

  // staging: segment (16KB = 256 rows x 64B) = 1024 chunks; thread j-th chunk = tid + j*256
  const char* aS[4]; const char* bS[4]; int dst[4];
  #pragma unroll
  for(int j=0;j<4;j++){
    int i = tid + j*256, rw = i >> 2;
    int sc = ((i & 3) ^ ((rw >> 1) & 3)) * 16;
    aS[j] = qx + ((long long)tileM*256 + rw)*din + sc;
    bS[j] = qw + ((long long)tileN*256 + rw)*din + sc;
    dst[j] = i*16;
  }

  // frag read addressing (32x32x32: lane -> row lane&31, k-chunk lane>>5)
  const int arow = wr*128 + (lane & 31);
  const int brow = wc*128 + (lane & 31);
  const int lxor = (lane >> 1) & 3, lhi = lane >> 5;

  i32x16 acc[4][4] = {};
  i32x4 af[4], bf[4];

#define STAGE(SEG, PTR, OFFBASE, KOFF) do{ _Pragma("unroll") \
    for(int j=0;j<4;j++) gload16(PTR[j] + (KOFF), lds + (OFFBASE) + dst[j]); }while(0)

#define READFRAGS(BUF, S) do{ \
    const int phys = ((((S)&1)*2 + lhi) ^ lxor) * 16; \
    const char* Ab_ = lds + AOFF(BUF, (S)>>1); \
    const char* Bb_ = lds + BOFF(BUF, (S)>>1); \
    _Pragma("unroll") \
    for(int mi=0;mi<4;++mi) af[mi] = *(const i32x4*)(Ab_ + (arow + mi*32)*64 + phys); \
    _Pragma("unroll") \
    for(int ni=0;ni<4;++ni) bf[ni] = *(const i32x4*)(Bb_ + (brow + ni*32)*64 + phys); }while(0)

#define MFMA16 do{ __builtin_amdgcn_s_setprio(1); _Pragma("unroll") \
    for(int mi=0;mi<4;++mi){ _Pragma("unroll") \
      for(int ni=0;ni<4;++ni) \
        acc[mi][ni] = __builtin_amdgcn_mfma_i32_32x32x32_i8(af[mi], bf[ni], acc[mi][ni], 0,0,0); } \
    __builtin_amdgcn_s_setprio(0); }while(0)

  // prologue: stage tile0 in order A0,B0,A1,B1
  STAGE(0, aS, AOFF(0,0), 0);
  STAGE(0, bS, BOFF(0,0), 0);
  STAGE(1, aS, AOFF(0,1), 64);
  STAGE(1, bS, BOFF(0,1), 64);

  for(int t = 0; t < nt; ++t){
    const int buf = t & 1, nb = buf ^ 1;
    const bool ld = (t + 1 < nt);
    const long long koff = (long long)(t + 1) * 128;

    // ph0: needs A[t]ks0+B[t]ks0 (t's loads 1-8) -> 8 newer in flight
    asm volatile("s_waitcnt vmcnt(8)" ::: "memory");
    __builtin_amdgcn_s_barrier();
    READFRAGS(buf, 0);
    if(ld) STAGE(0, aS, AOFF(nb,0), koff);
    MFMA16;
    // ph1: same ks64=0 regions (already synced) - no barrier
    READFRAGS(buf, 1);
    if(ld) STAGE(0, bS, BOFF(nb,0), koff);
    MFMA16;
    // ph2: needs t's loads 9-16; in flight after them = t+1's 8 just issued
    asm volatile("s_waitcnt vmcnt(8)" ::: "memory");
    __builtin_amdgcn_s_barrier();
    READFRAGS(buf, 2);
    if(ld) STAGE(1, aS, AOFF(nb,1), koff + 64);
    MFMA16;
    // ph3: no barrier
    READFRAGS(buf, 3);
    if(ld) STAGE(1, bS, BOFF(nb,1), koff + 64);
    MFMA16;
  }
#undef STAGE
#undef READFRAGS
#undef MFMA16

  // ---- epilogue (lgkm-only barriers; nt-stores never drained) ----
#define EBAR do{ asm volatile("s_waitcnt lgkmcnt(0)" ::: "memory"); \
                 __builtin_amdgcn_s_barrier(); }while(0)

  float mm = 0.f;
  for(int i = tid; i < nPart; i += 256) mm = fmaxf(mm, partials[i]);
  mm = wave_max(mm);
  EBAR;
  if(lane==0) ((float*)lds)[wid] = mm;
  EBAR;
  float xmax = 0.f;
  #pragma unroll
  for(int i=0;i<4;i++) xmax = fmaxf(xmax, ((float*)lds)[i]);

  const int n = 1 << *wbit;
  const float nm1 = (float)(n-1);
  const float xmaxc = fmaxf(xmax, 1e-8f);
  const float sx = __fdiv_rn(nm1, xmaxc);
  const float inv_sx = __fdiv_rn(xmaxc, nm1);
  const int colL = tileN*256 + wc*128 + (lane & 31);
  const int rowL = tileM*256 + wr*128;
  float invc[4], zp4[4]; int ci4[4];
  #pragma unroll
  for(int ni=0; ni<4; ++ni){
    int o = colL + ni*32;
    float sw = scale_w[o];
    float qbf = rintf(__fmul_rn(__fmul_rn(bias[o], sw), sx));
    qbf = fminf(fmaxf(qbf, -(float)(n+1)), (float)n);
    ci4[ni] = cint[o] + (int)qbf;
    invc[ni] = __fmul_rn(winv[o], inv_sx);
    zp4[ni]  = zp_w[o];
  }

  float* ebuf = (float*)lds;                 // 64 rows x 256 cols f32 = 64 KiB
  const int hi4 = 4*(lane >> 5);
  #pragma unroll
  for(int mi=0; mi<4; ++mi){
    int sav[16];
    #pragma unroll
    for(int q=0;q<4;++q)
      #pragma unroll
      for(int r2=0;r2<4;++r2)
        sav[q*4+r2] = Sa[rowL + mi*32 + r2 + 8*q + hi4];
    EBAR;                                    // prev flush reads complete
    #pragma unroll
    for(int ni=0; ni<4; ++ni){
      #pragma unroll
      for(int reg=0; reg<16; ++reg){
        int rit = (reg&3) + 8*(reg>>2) + hi4;
        int iv = acc[mi][ni][reg] + 128*sav[reg] + ci4[ni];
        float f = (float)iv + zp4[ni]*(float)sav[reg];
        ebuf[(wr*32 + rit)*256 + wc*128 + ni*32 + (lane&31)] = __fmul_rn(f, invc[ni]);
      }
    }
    EBAR;                                    // ebuf writes visible
    #pragma unroll
    for(int p=0; p<16; ++p){
      int idx = tid + p*256;                 // 0..4095
      int lr = idx >> 6, cc = (idx & 63)*4;
      f32x4 v = *(const f32x4*)&ebuf[lr*256 + cc];
      int gr = tileM*256 + (lr>>5)*128 + mi*32 + (lr&31);
      __builtin_nontemporal_store(v, (f32x4*)&out[(long long)gr*dout + tileN*256 + cc]);
    }
  }
#undef EBAR
}

extern "C" void kernel_launch(void* const* d_in, const int* in_sizes, int n_in,
                              void* d_out, int out_size, void* d_ws, size_t ws_size,
                              hipStream_t stream){
  const float* x    = (const float*)d_in[0];
  const float* w    = (const float*)d_in[1];
  const float* bias = (const float*)d_in[2];
  const int*   wbit = (const int*)d_in[3];
  int dout = in_sizes[2];
  int din  = in_sizes[1] / dout;
  int T    = in_sizes[0] / din;

  char* ws = (char*)d_ws;
  size_t off = 256;
  float* partials = (float*)(ws + off); off += 4*(size_t)dout;
  float* scale_w = (float*)(ws + off); off += 4*(size_t)dout;
  float* zp_w    = (float*)(ws + off); off += 4*(size_t)dout;
  float* winv    = (float*)(ws + off); off += 4*(size_t)dout;
  int*   cint    = (int*)(ws + off);   off += 4*(size_t)dout;
  int*   Sa      = (int*)(ws + off);   off += 4*(size_t)T;
  off = (off + 255) & ~(size_t)255;
  char*  qw      = ws + off;           off += (size_t)dout*din;
  char*  qx      = ws + off;           off += (size_t)T*din;

  long long n4 = (long long)T*din/4;
  k_wstat_xmax<<<dout, 256, 0, stream>>>(w, x, n4, wbit, scale_w, zp_w, winv, cint, qw, partials, din);
  k_xquant<<<T, 256, 0, stream>>>(x, wbit, partials, dout, qx, Sa, din);
  int nblk = (T/256) * (dout/256);
  k_gemm<<<nblk, 256, 131072, stream>>>(qx, qw, Sa, cint, scale_w, winv, zp_w, bias,
                                        wbit, partials, dout, (float*)d_out, T, dout, din);
}

// Round 15
// 79.462 us; speedup vs baseline: 1.7537x; 1.1150x over previous
//
#include <hip/hip_runtime.h>
#include <stdint.h>

typedef __attribute__((ext_vector_type(4))) int i32x4;
typedef __attribute__((ext_vector_type(4))) float f32x4;

__device__ inline float wave_max(float v){ for(int o=32;o;o>>=1) v=fmaxf(v,__shfl_xor(v,o)); return v; }
__device__ inline float wave_min(float v){ for(int o=32;o;o>>=1) v=fminf(v,__shfl_xor(v,o)); return v; }
__device__ inline int   wave_sum(int v){ for(int o=32;o;o>>=1) v+=__shfl_xor(v,o); return v; }

__device__ inline void gload16(const void* g, void* l){
  __builtin_amdgcn_global_load_lds((const __attribute__((address_space(1))) char*)g,
                                   (__attribute__((address_space(3))) char*)l, 16, 0, 0);
}

// ===== merged: w-stat/quant for row blockIdx.x  +  x-max partial slice (r13, proven) =====
__global__ void k_wstat_xmax(const float* __restrict__ w, const float* __restrict__ x,
                             long long n4, const int* __restrict__ wbit,
                             float* __restrict__ scale_w, float* __restrict__ zp_w,
                             float* __restrict__ winv, int* __restrict__ cint,
                             char* __restrict__ qw, float* __restrict__ partials, int din){
  int row = blockIdx.x, tid = threadIdx.x;
  int lane = tid & 63, wid = tid >> 6;
  // x-max slice (grid-stride)
  const float4* x4 = (const float4*)x;
  float m = 0.f;
  for(long long i = (long long)blockIdx.x*256 + tid; i < n4; i += (long long)gridDim.x*256){
    float4 v = x4[i];
    m = fmaxf(m, fmaxf(fmaxf(v.x,v.y),fmaxf(v.z,v.w)));
  }
  m = wave_max(m);
  __shared__ float sxm[4];
  if(lane==0) sxm[wid] = m;
  // w row stats
  const float4* wr4 = (const float4*)(w + (long long)row*din);
  float4 a = wr4[tid*2], b = wr4[tid*2+1];
  float v[8] = {a.x,a.y,a.z,a.w,b.x,b.y,b.z,b.w};
  float mn = v[0], mx = v[0];
  for(int j=1;j<8;j++){ mn=fminf(mn,v[j]); mx=fmaxf(mx,v[j]); }
  float wmn = wave_min(mn), wmx = wave_max(mx);
  __shared__ float smn[4], smx[4];
  __shared__ float s_sw, s_zp;
  if(lane==0){ smn[wid]=wmn; smx[wid]=wmx; }
  __syncthreads();
  if(tid==0){
    partials[row] = fmaxf(fmaxf(sxm[0],sxm[1]),fmaxf(sxm[2],sxm[3]));
    float fmn = fminf(fminf(smn[0],smn[1]),fminf(smn[2],smn[3]));
    float fmx = fmaxf(fmaxf(smx[0],smx[1]),fmaxf(smx[2],smx[3]));
    int n = 1 << *wbit;
    float nm1 = (float)(n-1);
    float rngc = fmaxf(__fsub_rn(fmx, fmn), 1e-8f);
    float sw = __fdiv_rn(nm1, rngc);
    float zp = __fmul_rn(sw, fmn);
    s_sw = sw; s_zp = zp;
    scale_w[row] = sw; zp_w[row] = zp;
    winv[row] = __fdiv_rn(rngc, nm1);
  }
  __syncthreads();
  float sw = s_sw, zp = s_zp;
  int qsum = 0; uint32_t lo = 0, hi = 0;
  for(int j=0;j<8;j++){
    int q = (int)rintf(__fsub_rn(__fmul_rn(sw, v[j]), zp));   // exact replication, no fma
    qsum += q;
    uint32_t u = (uint32_t)((q - 128) & 0xff);
    if(j<4) lo |= u << (8*j); else hi |= u << (8*(j-4));
  }
  uint32_t* qrow = (uint32_t*)(qw + (long long)row*din);
  qrow[tid*2] = lo; qrow[tid*2+1] = hi;
  int wsum = wave_sum(qsum);
  __shared__ int ssum[4];
  if(lane==0) ssum[wid] = wsum;
  __syncthreads();
  if(tid==0){
    int Sb = ssum[0]+ssum[1]+ssum[2]+ssum[3];
    cint[row] = 128*Sb - 128*128*din;
  }
}

// one block (256 thr) per token row; reduces partials inline (r13, proven)
__global__ void k_xquant(const float* __restrict__ x, const int* __restrict__ wbit,
                         const float* __restrict__ partials, int nPart,
                         char* __restrict__ qx, int* __restrict__ Sa, int din){
  int row = blockIdx.x, tid = threadIdx.x;
  int lane = tid & 63, wid = tid >> 6;
  float mm = 0.f;
  for(int i=tid;i<nPart;i+=256) mm = fmaxf(mm, partials[i]);
  mm = wave_max(mm);
  __shared__ float sm[4];
  if(lane==0) sm[wid] = mm;
  __syncthreads();
  const float xmax = fmaxf(fmaxf(sm[0],sm[1]),fmaxf(sm[2],sm[3]));
  int n = 1 << *wbit;
  float nm1 = (float)(n-1);
  float sx = __fdiv_rn(nm1, fmaxf(xmax, 1e-8f));
  const float4* xr4 = (const float4*)(x + (long long)row*din);
  float4 a = xr4[tid*2], b = xr4[tid*2+1];
  float v[8] = {a.x,a.y,a.z,a.w,b.x,b.y,b.z,b.w};
  int qsum = 0; uint32_t lo = 0, hi = 0;
  for(int j=0;j<8;j++){
    int q = (int)rintf(__fmul_rn(sx, v[j]));
    qsum += q;
    uint32_t u = (uint32_t)((q - 128) & 0xff);
    if(j<4) lo |= u << (8*j); else hi |= u << (8*(j-4));
  }
  uint32_t* qrow = (uint32_t*)(qx + (long long)row*din);
  qrow[tid*2] = lo; qrow[tid*2+1] = hi;
  int wsum = wave_sum(qsum);
  __shared__ int ssum[4];
  if(lane==0) ssum[wid] = wsum;
  __syncthreads();
  if(tid==0) Sa[row] = ssum[0]+ssum[1]+ssum[2]+ssum[3];
}

// ======= 256x256 i8 GEMM (r11, proven: 4-phase counted-vmcnt, XCD-rect, drain-free epi) =======
__global__ __launch_bounds__(512, 2) void k_gemm(
    const char* __restrict__ qx, const char* __restrict__ qw,
    const int* __restrict__ Sa, const int* __restrict__ cint,
    const float* __restrict__ scale_w, const float* __restrict__ winv,
    const float* __restrict__ zp_w, const float* __restrict__ bias,
    const int* __restrict__ wbit, const float* __restrict__ partials, int nPart,
    float* __restrict__ out, int T, int dout, int din){
  extern __shared__ char lds[];   // [buf:2][op:2(A,B)][ks:2][16384]
  const int tid = threadIdx.x, lane = tid & 63, wid = tid >> 6;
  const int wr = wid >> 2, wc = wid & 3;
  const int nt = din / 128;

  // ---- XCD-rect block -> tile mapping ----
  const int bid = blockIdx.x;
  const int nTN = dout >> 8, nTM = T >> 8;
  int tileM, tileN;
  if(nTM == 32 && nTN == 8){
    const int rect = bid & 7, loc = bid >> 3;
    tileM = (rect >> 1)*8 + (loc & 7);
    tileN = (rect & 1)*4 + (loc >> 3);
  } else {
    tileN = bid % nTN; tileM = bid / nTN;
  }

  // staging: half-tile = 1024 chunks of 16B; thread handles chunks {tid, tid+512}
  const int i0 = tid, i1 = tid + 512;
  const int r0 = i0 >> 2, r1 = i1 >> 2;
  const int sc0 = ((i0 & 3) ^ ((r0 >> 1) & 3)) * 16;
  const int sc1 = ((i1 & 3) ^ ((r1 >> 1) & 3)) * 16;
  const char* aS0 = qx + ((long long)tileM*256 + r0)*din + sc0;
  const char* aS1 = qx + ((long long)tileM*256 + r1)*din + sc1;
  const char* bS0 = qw + ((long long)tileN*256 + r0)*din + sc0;
  const char* bS1 = qw + ((long long)tileN*256 + r1)*din + sc1;
  const int d0 = i0*16, d1 = i1*16;

  // ds_read addressing
  const int physo = (((lane >> 4) ^ ((lane >> 1) & 3)) * 16);
  const int arowL = wr*128 + (lane & 15);
  const int browL = wc*64  + (lane & 15);

  i32x4 acc[8][4] = {};
  i32x4 af[4], bf[4];

#define STAGE_A(KS, KOFF, NB) do{ \
    gload16(aS0 + (KOFF) + (KS)*64, (NB) + (KS)*16384 + d0); \
    gload16(aS1 + (KOFF) + (KS)*64, (NB) + (KS)*16384 + d1); }while(0)
#define STAGE_B(KS, KOFF, NB) do{ \
    gload16(bS0 + (KOFF) + (KS)*64, (NB) + 32768 + (KS)*16384 + d0); \
    gload16(bS1 + (KOFF) + (KS)*64, (NB) + 32768 + (KS)*16384 + d1); }while(0)

  // ---- prologue: epilogue-operand prefetch (completes during early K-tiles) ----
  const int colL = tileN*256 + wc*64 + (lane & 15);
  const int rowL = tileM*256 + wr*128 + ((lane >> 4) * 4);
  float pm[4];
  #pragma unroll
  for(int j=0;j<4;j++) pm[j] = partials[(tid + j*512) & (nPart-1)];
  float p_sw[4], p_winv[4], p_zp[4], p_bias[4]; int p_ci[4];
  #pragma unroll
  for(int ni=0; ni<4; ++ni){
    int o = colL + ni*16;
    p_sw[ni] = scale_w[o]; p_winv[ni] = winv[o];
    p_zp[ni] = zp_w[o];    p_bias[ni] = bias[o];
    p_ci[ni] = cint[o];
  }
  int p_sa[8][4];
  #pragma unroll
  for(int mi=0; mi<8; ++mi)
    #pragma unroll
    for(int r=0; r<4; ++r) p_sa[mi][r] = Sa[rowL + mi*16 + r];
  const int nbit = 1 << *wbit;

  // ---- prologue: stage tile 0 in consumption order; land ks0; barrier ----
  STAGE_A(0, 0, lds); STAGE_B(0, 0, lds);
  STAGE_A(1, 0, lds); STAGE_B(1, 0, lds);
  asm volatile("s_waitcnt vmcnt(4)" ::: "memory");
  __builtin_amdgcn_s_barrier();

  for(int t = 0; t < nt; ++t){
    char* Ab = lds + (t & 1)*65536;          // A base (current buf)
    char* Bb = Ab + 32768;                   // B base
    char* NB = lds + ((t & 1)^1)*65536;      // next buf
    const bool ld = (t + 1 < nt);
    const int koff = (t + 1)*128;

#define PH(MH, KS, DO_B, STAGE_STMT, VM_STMT) do{ \
    if(DO_B){ _Pragma("unroll") \
      for(int ni=0;ni<4;++ni) bf[ni] = *(const i32x4*)(Bb + (KS)*16384 + (browL + ni*16)*64 + physo); } \
    _Pragma("unroll") \
    for(int mi=0;mi<4;++mi) af[mi] = *(const i32x4*)(Ab + (KS)*16384 + (arowL + (MH)*64 + mi*16)*64 + physo); \
    STAGE_STMT; \
    __builtin_amdgcn_s_barrier(); \
    __builtin_amdgcn_s_setprio(1); \
    _Pragma("unroll") \
    for(int mi=0;mi<4;++mi){ _Pragma("unroll") \
      for(int ni=0;ni<4;++ni) \
        acc[(MH)*4+mi][ni] = __builtin_amdgcn_mfma_i32_16x16x64_i8(af[mi], bf[ni], acc[(MH)*4+mi][ni], 0,0,0); } \
    __builtin_amdgcn_s_setprio(0); \
    VM_STMT; \
    __builtin_amdgcn_s_barrier(); }while(0)

    PH(0, 0, true,  if(ld) STAGE_A(0, koff, NB), );
    PH(1, 0, false, if(ld) STAGE_B(0, koff, NB),
       if(ld){ asm volatile("s_waitcnt vmcnt(4)" ::: "memory"); }
       else  { asm volatile("s_waitcnt vmcnt(0)" ::: "memory"); });
    PH(0, 1, true,  if(ld) STAGE_A(1, koff, NB), );
    PH(1, 1, false, if(ld) STAGE_B(1, koff, NB),
       if(ld){ asm volatile("s_waitcnt vmcnt(4)" ::: "memory"); });
#undef PH
  }

  // ---- epilogue (lgkm-only barriers; nt-stores never drained) ----
#define EBAR do{ asm volatile("s_waitcnt lgkmcnt(0)" ::: "memory"); \
                 __builtin_amdgcn_s_barrier(); }while(0)

  float mm = fmaxf(fmaxf(pm[0],pm[1]),fmaxf(pm[2],pm[3]));
  mm = wave_max(mm);
  EBAR;                                   // all main-loop LDS reads complete
  if(lane==0) ((float*)lds)[wid] = mm;
  EBAR;
  float xmax = 0.f;
  #pragma unroll
  for(int i=0;i<8;i++) xmax = fmaxf(xmax, ((float*)lds)[i]);

  const float nm1 = (float)(nbit-1);
  const float xmaxc = fmaxf(xmax, 1e-8f);
  const float sx = __fdiv_rn(nm1, xmaxc);
  const float inv_sx = __fdiv_rn(xmaxc, nm1);
  float invc[4], zp4[4]; int ci4[4];
  #pragma unroll
  for(int ni=0; ni<4; ++ni){
    float qbf = rintf(__fmul_rn(__fmul_rn(p_bias[ni], p_sw[ni]), sx));
    qbf = fminf(fmaxf(qbf, -(float)(nbit+1)), (float)nbit);
    ci4[ni] = p_ci[ni] + (int)qbf;
    invc[ni] = __fmul_rn(p_winv[ni], inv_sx);
    zp4[ni]  = p_zp[ni];
  }

  float* ebuf = (float*)lds;                 // 32 rows x 256 cols f32 = 32 KiB
  const int lwr  = wr*16 + ((lane >> 4) * 4);
  const int lcol = wc*64 + (lane & 15);
  #pragma unroll
  for(int mi=0; mi<8; ++mi){
    EBAR;                                    // prev-iter flush reads complete
    #pragma unroll
    for(int ni=0; ni<4; ++ni){
      #pragma unroll
      for(int r=0; r<4; ++r){
        int iv = acc[mi][ni][r] + 128*p_sa[mi][r] + ci4[ni];
        float f = (float)iv + zp4[ni]*(float)p_sa[mi][r];
        int row = lwr + r, col = lcol + ni*16;
        ebuf[row*256 + (col ^ (((row>>2)&3)<<4))] = __fmul_rn(f, invc[ni]);
      }
    }
    EBAR;                                    // ebuf writes visible
    #pragma unroll
    for(int p=0; p<4; ++p){
      int idx = tid + p*512;                 // 0..2047
      int lr = idx >> 6, cc = (idx & 63)*4;
      f32x4 v = *(const f32x4*)&ebuf[lr*256 + (cc ^ (((lr>>2)&3)<<4))];
      int gr = tileM*256 + (lr>>4)*128 + mi*16 + (lr&15);
      __builtin_nontemporal_store(v, (f32x4*)&out[(long long)gr*dout + tileN*256 + cc]);
    }
  }
#undef EBAR
}

extern "C" void kernel_launch(void* const* d_in, const int* in_sizes, int n_in,
                              void* d_out, int out_size, void* d_ws, size_t ws_size,
                              hipStream_t stream){
  const float* x    = (const float*)d_in[0];
  const float* w    = (const float*)d_in[1];
  const float* bias = (const float*)d_in[2];
  const int*   wbit = (const int*)d_in[3];
  int dout = in_sizes[2];
  int din  = in_sizes[1] / dout;
  int T    = in_sizes[0] / din;

  char* ws = (char*)d_ws;
  size_t off = 256;
  float* partials = (float*)(ws + off); off += 4*(size_t)dout;
  float* scale_w = (float*)(ws + off); off += 4*(size_t)dout;
  float* zp_w    = (float*)(ws + off); off += 4*(size_t)dout;
  float* winv    = (float*)(ws + off); off += 4*(size_t)dout;
  int*   cint    = (int*)(ws + off);   off += 4*(size_t)dout;
  int*   Sa      = (int*)(ws + off);   off += 4*(size_t)T;
  off = (off + 255) & ~(size_t)255;
  char*  qw      = ws + off;           off += (size_t)dout*din;
  char*  qx      = ws + off;           off += (size_t)T*din;

  long long n4 = (long long)T*din/4;
  k_wstat_xmax<<<dout, 256, 0, stream>>>(w, x, n4, wbit, scale_w, zp_w, winv, cint, qw, partials, din);
  k_xquant<<<T, 256, 0, stream>>>(x, wbit, partials, dout, qx, Sa, din);
  int nblk = (T/256) * (dout/256);
  k_gemm<<<nblk, 512, 131072, stream>>>(qx, qw, Sa, cint, scale_w, winv, zp_w, bias,
                                        wbit, partials, dout, (float*)d_out, T, dout, din);
}